// Round 4
// baseline (644.876 us; speedup 1.0000x reference)
//
#include <hip/hip_runtime.h>
#include <hip/hip_bf16.h>
#include <hip/hip_cooperative_groups.h>

namespace cg = cooperative_groups;

// out[b] = M[b] @ X[b] + bias2, X = x_in[b] as [192,16384]
//   G[b] = X X^T ; Wq'=w_q@w_split etc.; Wo2=w_out@w_proj; bias2=w_out@b_proj
//   qn[d]=sqrt(Wq'[d] G Wq'[d]^T); kn[cc]=sqrt(Wk'[cc] G Wk'[cc]^T)
//   A = softmax_rows(Wk' G Wq'^T / (kn ⊗ qn)); M = Wo2 (A Wv')
// 4 launches: gram4 (partials) -> gsum+fold -> mid (cooperative, qn/attn/m) -> final3.

static constexpr int B_ = 8;
static constexpr int C_ = 192;
static constexpr int N_ = 16384;
static constexpr int CC2 = C_ * C_;
static constexpr int NCHUNK = 32;

using u16x8 = __attribute__((ext_vector_type(8))) unsigned short;
using bf16x8 = __attribute__((ext_vector_type(8))) __bf16;
using f32x4 = __attribute__((ext_vector_type(4))) float;
using f32x16 = __attribute__((ext_vector_type(16))) float;

__device__ __forceinline__ unsigned short f2bf(float f) {
  unsigned int u = __builtin_bit_cast(unsigned int, f);
  u += 0x7FFFu + ((u >> 16) & 1u);   // RNE
  return (unsigned short)(u >> 16);
}
__device__ __forceinline__ unsigned int pk2bf(float x, float y) {
  return (unsigned)f2bf(x) | ((unsigned)f2bf(y) << 16);
}
__device__ __forceinline__ f32x4 mfma16(u16x8 a, u16x8 b, f32x4 c) {
  return __builtin_amdgcn_mfma_f32_16x16x32_bf16(
      __builtin_bit_cast(bf16x8, a), __builtin_bit_cast(bf16x8, b), c, 0, 0, 0);
}
__device__ __forceinline__ f32x16 mfma32(u16x8 a, u16x8 b, f32x16 c) {
  return __builtin_amdgcn_mfma_f32_32x32x16_bf16(
      __builtin_bit_cast(bf16x8, a), __builtin_bit_cast(bf16x8, b), c, 0, 0, 0);
}

// ---------------- Gram: 32x32x16 MFMA, 3-wave blocks, dbuf pipeline ----------------
// grid (32 k-chunks, 2 row-halves, 8 batches) = 512 blocks (2/CU), 192 thr (3 waves).
// Wave w owns 32 G-rows; block stages all 192 X-rows x 64 cols per stage.
template <bool PART>
__global__ __launch_bounds__(192, 2) void gram4_kernel(const float* __restrict__ xin,
                                                       float* __restrict__ dst) {
  const int b = blockIdx.z, half = blockIdx.y, ch = blockIdx.x;
  const int k0 = ch * 512;
  __shared__ unsigned short Xs[2][C_][72];         // dbuf, pitch 72
  const int tid = threadIdx.x;                     // 0..191
  const int wv = tid >> 6;                         // 0..2
  const int lane = tid & 63;
  const int m32 = lane & 31;
  const int hi = lane >> 5;                        // k-half of the 32x32x16 frag
  const int arow0 = half * 96 + wv * 32;
  const int cth = tid >> 4;                        // 0..11 (staging row group)
  const int k4 = tid & 15;
  const float* xb = xin + (size_t)b * C_ * N_;

  f32x16 acc[6];
#pragma unroll
  for (int j = 0; j < 6; ++j) acc[j] = (f32x16)0.0f;

  float4 ld[16];
  auto load_stage = [&](int kbase) {
#pragma unroll
    for (int j = 0; j < 16; ++j)
      ld[j] = *(const float4*)(xb + (size_t)(j * 12 + cth) * N_ + kbase + k4 * 4);
  };
  auto write_stage = [&](int buf) {
#pragma unroll
    for (int j = 0; j < 16; ++j) {
      uint2 pk;
      pk.x = pk2bf(ld[j].x, ld[j].y);
      pk.y = pk2bf(ld[j].z, ld[j].w);
      *(uint2*)&Xs[buf][j * 12 + cth][k4 * 4] = pk;   // ds_write_b64
    }
  };

  load_stage(k0);
  write_stage(0);
  __syncthreads();
  for (int s = 0; s < 8; ++s) {                    // 8 stages of 64 k
    if (s < 7) load_stage(k0 + (s + 1) * 64);      // prefetch overlaps MFMA
    const int cb = s & 1;
#pragma unroll
    for (int ks = 0; ks < 4; ++ks) {               // four K=16 steps
      const int koff = ks * 16 + hi * 8;
      u16x8 a = *(const u16x8*)&Xs[cb][arow0 + m32][koff];
#pragma unroll
      for (int ct = 0; ct < 6; ++ct) {
        u16x8 bb = *(const u16x8*)&Xs[cb][ct * 32 + m32][koff];
        acc[ct] = mfma32(a, bb, acc[ct]);
      }
    }
    if (s < 7) {
      write_stage(cb ^ 1);   // cb^1 last read a full barrier ago
      __syncthreads();
    }
  }
  float* outp = PART ? dst + ((size_t)b * NCHUNK + ch) * CC2
                     : dst + (size_t)b * CC2;
#pragma unroll
  for (int ct = 0; ct < 6; ++ct)
#pragma unroll
    for (int reg = 0; reg < 16; ++reg) {
      // 32x32 C/D: col=lane&31, row=(reg&3)+8*(reg>>2)+4*(lane>>5)  [m74/m101]
      int row = arow0 + (reg & 3) + 8 * (reg >> 2) + 4 * hi;
      int col = ct * 32 + m32;
      if (PART) outp[row * C_ + col] = acc[ct][reg];
      else atomicAdd(&outp[row * C_ + col], acc[ct][reg]);
    }
}

// ---------------- gsum (32 partial slabs -> G) + weight-fold, one launch ----------
__global__ void gsumfold_kernel(const float* __restrict__ P, float* __restrict__ G,
                                const float* __restrict__ wsplit, const float* __restrict__ wq,
                                const float* __restrict__ wk, const float* __restrict__ wv,
                                const float* __restrict__ wproj, const float* __restrict__ bproj,
                                const float* __restrict__ wout,
                                float* __restrict__ Wq, float* __restrict__ WqT,
                                float* __restrict__ Wk, float* __restrict__ Wv,
                                float* __restrict__ Wo2, float* __restrict__ bias2,
                                int do_gsum) {
  const int gx = blockIdx.x, tid = threadIdx.x;
  if (gx < 288) {                                  // gsum part: 288 blocks
    if (!do_gsum) return;
    const int b = gx / 36, jb = gx % 36;
    const int j = (jb * 256 + tid) * 4;
    const float* base = P + (size_t)b * NCHUNK * CC2 + j;
    float4 s = {0.f, 0.f, 0.f, 0.f};
#pragma unroll
    for (int ch = 0; ch < NCHUNK; ++ch) {
      float4 v = *(const float4*)(base + (size_t)ch * CC2);
      s.x += v.x; s.y += v.y; s.z += v.z; s.w += v.w;
    }
    *(float4*)(G + (size_t)b * CC2 + j) = s;
    return;
  }
  // fold part: 576 blocks
  const int idx = (gx - 288) * 256 + tid;
  if (idx < C_) {
    float s = 0.f;
    for (int c = 0; c < C_; ++c) s += wout[idx * C_ + c] * bproj[c];
    bias2[idx] = s;
  }
  if (idx >= 4 * CC2) return;
  const int which = idx / CC2;
  const int rem = idx % CC2;
  const int o = rem / C_, c = rem % C_;
  const float* A = (which == 0) ? wq : (which == 1) ? wk : (which == 2) ? wv : wout;
  const float* Bm = (which == 3) ? wproj : wsplit;
  float s = 0.f;
  for (int e = 0; e < C_; ++e) s += A[o * C_ + e] * Bm[e * C_ + c];
  if (which == 0) { Wq[rem] = s; WqT[c * C_ + o] = s; }
  else if (which == 1) Wk[rem] = s;
  else if (which == 2) Wv[rem] = s;
  else Wo2[rem] = s;
}

// ---------------- mid: cooperative. phase1 qn | phase2 attn+Tv | phase3 M ---------
__device__ __forceinline__ float block_sum192(float v, float* wred, int t) {
#pragma unroll
  for (int off = 32; off > 0; off >>= 1) v += __shfl_down(v, off);
  if ((t & 63) == 0) wred[t >> 6] = v;
  __syncthreads();
  float r = wred[0] + wred[1] + wred[2];
  __syncthreads();
  return r;
}
__device__ __forceinline__ float block_max192(float v, float* wred, int t) {
#pragma unroll
  for (int off = 32; off > 0; off >>= 1) v = fmaxf(v, __shfl_down(v, off));
  if ((t & 63) == 0) wred[t >> 6] = v;
  __syncthreads();
  float r = fmaxf(fmaxf(wred[0], wred[1]), wred[2]);
  __syncthreads();
  return r;
}

__global__ __launch_bounds__(192) void mid_kernel(const float* __restrict__ G,
                                                  const float* __restrict__ Wq,
                                                  const float* __restrict__ WqT,
                                                  const float* __restrict__ Wk,
                                                  const float* __restrict__ Wv,
                                                  const float* __restrict__ Wo2,
                                                  float* __restrict__ qn,
                                                  float* __restrict__ Tv,
                                                  float* __restrict__ Mw) {
  cg::grid_group grid = cg::this_grid();
  const int b = blockIdx.y, r = blockIdx.x, t = threadIdx.x;
  const float* Gb = G + (size_t)b * CC2;
  __shared__ float sh[C_];
  __shared__ float wred[4];

  // phase 1: qn[b,r] = sqrt(Wq[r] G Wq[r]^T)
  float sq = 0.f;
  for (int c = 0; c < C_; ++c) sq += Wq[r * C_ + c] * Gb[c * C_ + t];
  float tot = block_sum192(sq * Wq[r * C_ + t], wred, t);
  if (t == 0) qn[b * C_ + r] = fmaxf(sqrtf(fmaxf(tot, 0.f)), 1e-12f);
  grid.sync();

  // phase 2: attn row cc=r -> Tv row
  float tk = 0.f;
  for (int c = 0; c < C_; ++c) tk += Wk[r * C_ + c] * Gb[c * C_ + t];
  sh[t] = tk;
  float kn2 = block_sum192(tk * Wk[r * C_ + t], wred, t);  // barrier makes sh visible
  float knv = fmaxf(sqrtf(fmaxf(kn2, 0.f)), 1e-12f);
  float lg = 0.f;
  for (int c = 0; c < C_; ++c) lg += sh[c] * WqT[c * C_ + t];
  lg /= (knv * qn[b * C_ + t]);
  float mx = block_max192(lg, wred, t);
  float e = expf(lg - mx);
  float se = block_sum192(e, wred, t);                     // barrier: all done reading sh
  float a = e / se;
  sh[t] = a;
  __syncthreads();
  float sv = 0.f;
  for (int c = 0; c < C_; ++c) sv += sh[c] * Wv[c * C_ + t];
  Tv[((size_t)b * C_ + r) * C_ + t] = sv;
  grid.sync();

  // phase 3: M row i=r
  float sm = 0.f;
  for (int c = 0; c < C_; ++c) sm += Wo2[r * C_ + c] * Tv[((size_t)b * C_ + c) * C_ + t];
  Mw[((size_t)b * C_ + r) * C_ + t] = sm;
}

// ---------------- final: persistent 4-tile dbuf, out = M X + bias2 ----------------
// 256 blocks (b = beta>>5, q = beta&31 -> tiles 4q..4q+3 of 128 cols), 384 thr.
// XOR-swizzled LDS (final2 scheme): X[c][p] at Ts[p*192 + 8*((c>>3)^(p&7)) + (c&7)].
__global__ __launch_bounds__(384) void final3_kernel(const float* __restrict__ xin,
                                                     const float* __restrict__ Mw,
                                                     const float* __restrict__ bias2,
                                                     float* __restrict__ out) {
  const int beta = blockIdx.x;
  const int b = beta >> 5, q = beta & 31;
  __shared__ unsigned short Ts[2][128 * 192];      // 2 x 48 KB
  const int tid = threadIdx.x;
  const int wv = tid >> 6;
  const int lane = tid & 63;
  const int ln = lane & 15, mq = lane >> 4;
  const float* Mb = Mw + (size_t)b * CC2;
  const float* xb = xin + (size_t)b * C_ * N_;

  u16x8 afr[6][2];
  float bo[2][4];
#pragma unroll
  for (int i = 0; i < 2; ++i) {
    int row = 32 * wv + 16 * i + ln;
#pragma unroll
    for (int kc = 0; kc < 6; ++kc) {
      const float* src = Mb + row * C_ + kc * 32 + mq * 8;
      float4 u0 = *(const float4*)(src);
      float4 u1 = *(const float4*)(src + 4);
      u16x8 a;
      a[0] = f2bf(u0.x); a[1] = f2bf(u0.y); a[2] = f2bf(u0.z); a[3] = f2bf(u0.w);
      a[4] = f2bf(u1.x); a[5] = f2bf(u1.y); a[6] = f2bf(u1.z); a[7] = f2bf(u1.w);
      afr[kc][i] = a;
    }
#pragma unroll
    for (int r = 0; r < 4; ++r) bo[i][r] = bias2[32 * wv + 16 * i + mq * 4 + r];
  }

  float4 ld[16];
  auto load_tile = [&](int it) {
    const int p0 = (q * 4 + it) * 128;
#pragma unroll
    for (int j = 0; j < 16; ++j) {
      int lin = j * 384 + tid;
      int c = lin >> 5, p4 = lin & 31;
      ld[j] = *(const float4*)(xb + (size_t)c * N_ + p0 + p4 * 4);
    }
  };
  auto stage = [&](int buf) {
#pragma unroll
    for (int j = 0; j < 16; ++j) {
      int lin = j * 384 + tid;
      int c = lin >> 5, p4 = lin & 31;
#pragma unroll
      for (int jj = 0; jj < 4; ++jj) {
        int e = (jj + (p4 >> 1)) & 3;              // rotate: 8 distinct p&7 keys/inst
        float val = (e == 0) ? ld[j].x : (e == 1) ? ld[j].y : (e == 2) ? ld[j].z : ld[j].w;
        int p = p4 * 4 + e;
        Ts[buf][p * 192 + ((((c >> 3) ^ (p & 7)) << 3) | (c & 7))] = f2bf(val);
      }
    }
  };

  load_tile(0);
  for (int it = 0; it < 4; ++it) {
    const int bf = it & 1;
    stage(bf);
    __syncthreads();
    if (it < 3) load_tile(it + 1);                 // loads fly during compute+stores
    const int p0 = (q * 4 + it) * 128;
#pragma unroll
    for (int pt = 0; pt < 8; ++pt) {
      const int p = pt * 16 + ln;
      f32x4 acc0 = (f32x4)0.0f, acc1 = (f32x4)0.0f;
#pragma unroll
      for (int kc = 0; kc < 6; ++kc) {
        u16x8 bfr = *(const u16x8*)&Ts[bf][p * 192 + (((kc * 4 + mq) ^ (p & 7)) << 3)];
        acc0 = mfma16(afr[kc][0], bfr, acc0);
        acc1 = mfma16(afr[kc][1], bfr, acc1);
      }
#pragma unroll
      for (int r = 0; r < 4; ++r) {
        int row0 = 32 * wv + mq * 4 + r;
        int row1 = row0 + 16;
        int pp = p0 + pt * 16 + ln;
        out[((size_t)b * C_ + row0) * N_ + pp] = acc0[r] + bo[0][r];
        out[((size_t)b * C_ + row1) * N_ + pp] = acc1[r] + bo[1][r];
      }
    }
    // next stage(bf^1) needs no barrier: it writes the other buffer; Ts[bf] reuse
    // at it+2 is fenced by the barrier after stage(it+1).
  }
}

extern "C" void kernel_launch(void* const* d_in, const int* in_sizes, int n_in,
                              void* d_out, int out_size, void* d_ws, size_t ws_size,
                              hipStream_t stream) {
  const float* xin    = (const float*)d_in[0];
  const float* wsplit = (const float*)d_in[1];
  const float* wq     = (const float*)d_in[2];
  const float* wk     = (const float*)d_in[3];
  const float* wv     = (const float*)d_in[4];
  const float* wproj  = (const float*)d_in[5];
  const float* bproj  = (const float*)d_in[6];
  const float* wout   = (const float*)d_in[7];
  float* out = (float*)d_out;

  float* ws = (float*)d_ws;
  float* G     = ws;                         // B*CC2
  float* Wq    = G + (size_t)B_ * CC2;       // CC2
  float* WqT   = Wq + CC2;
  float* Wk    = WqT + CC2;
  float* Wv    = Wk + CC2;
  float* Wo2   = Wv + CC2;
  float* bias2 = Wo2 + CC2;                  // 256
  float* Tv    = bias2 + 256;                // B*CC2
  float* Mw    = Tv + (size_t)B_ * CC2;
  float* qn    = Mw + (size_t)B_ * CC2;      // 256*B
  float* P     = qn + 256 * B_;              // B*NCHUNK*CC2 (37.7 MB) if it fits

  size_t base_floats = (size_t)(P - ws);
  size_t need_bytes = (base_floats + (size_t)B_ * NCHUNK * CC2) * sizeof(float);
  int use_partials = ws_size >= need_bytes ? 1 : 0;

  if (use_partials) {
    gram4_kernel<true><<<dim3(NCHUNK, 2, B_), 192, 0, stream>>>(xin, P);
  } else {
    hipMemsetAsync(G, 0, (size_t)B_ * CC2 * sizeof(float), stream);
    gram4_kernel<false><<<dim3(NCHUNK, 2, B_), 192, 0, stream>>>(xin, G);
  }
  gsumfold_kernel<<<288 + 576, 256, 0, stream>>>(P, G, wsplit, wq, wk, wv, wproj, bproj,
                                                 wout, Wq, WqT, Wk, Wv, Wo2, bias2,
                                                 use_partials);
  {
    void* args[] = {(void*)&G, (void*)&Wq, (void*)&WqT, (void*)&Wk, (void*)&Wv,
                    (void*)&Wo2, (void*)&qn, (void*)&Tv, (void*)&Mw};
    hipLaunchCooperativeKernel((void*)mid_kernel, dim3(C_, B_), dim3(192), args, 0, stream);
  }
  final3_kernel<<<256, 384, 0, stream>>>(xin, Mw, bias2, out);
}